// Round 3
// baseline (120.889 us; speedup 1.0000x reference)
//
#include <hip/hip_runtime.h>
#include <hip/hip_bf16.h>

typedef float  f32x4  __attribute__((ext_vector_type(4)));
typedef short  s16x8  __attribute__((ext_vector_type(8)));
typedef unsigned short u16x8 __attribute__((ext_vector_type(8)));

#define T_  512
#define D_  512
#define BTD 4194304   // 16*512*512
#define SCALE_Q 0.044194173824159216f   // 1/sqrt(512)

static __device__ __forceinline__ unsigned short f2bf(float f) {
  unsigned u = __builtin_bit_cast(unsigned, f);
  u += 0x7fffu + ((u >> 16) & 1u);
  return (unsigned short)(u >> 16);
}

static __device__ __forceinline__ void gload_lds16(const void* g, void* l) {
  __builtin_amdgcn_global_load_lds(
      (__attribute__((address_space(1))) void*)(g),
      (__attribute__((address_space(3))) void*)(l),
      16, 0, 0);
}

static __device__ __forceinline__ float redmax16(float v) {
  v = fmaxf(v, __shfl_xor(v, 1)); v = fmaxf(v, __shfl_xor(v, 2));
  v = fmaxf(v, __shfl_xor(v, 4)); v = fmaxf(v, __shfl_xor(v, 8));
  return v;
}
static __device__ __forceinline__ float redsum16(float v) {
  v += __shfl_xor(v, 1); v += __shfl_xor(v, 2);
  v += __shfl_xor(v, 4); v += __shfl_xor(v, 8);
  return v;
}

// ---------------------------------------------------------------------------
// 128x128-tile bt-GEMM mainloop (proven): C += A[M,K] * B[N,K]^T.
// ---------------------------------------------------------------------------
__device__ __forceinline__ void gemm_mainloop(
    const unsigned short* __restrict__ A,
    const unsigned short* __restrict__ B,
    int lda, int ldb, int ksteps,
    unsigned short* ldsA, unsigned short* ldsB,
    f32x4 acc[4][4])
{
  const int tid  = threadIdx.x;
  const int lane = tid & 63;
  const int wave = tid >> 6;
  const int wr = wave >> 1, wc = wave & 1;

  const int c0 = wave, c1 = wave + 4;
  const int ks0 = c0 >> 1, r00 = (c0 & 1) * 64;
  const int ks1 = c1 >> 1, r01 = (c1 & 1) * 64;

  const char* ldsAc = (const char*)ldsA;
  const char* ldsBc = (const char*)ldsB;
  const int offA = (lane >> 4) * 2048 + (wr * 64 + (lane & 15)) * 16;
  const int offB = (lane >> 4) * 2048 + (wc * 64 + (lane & 15)) * 16;

  for (int kt = 0; kt < ksteps; ++kt) {
    const unsigned short* Ak = A + kt * 32;
    const unsigned short* Bk = B + kt * 32;
    gload_lds16(Ak + (size_t)(r00 + lane) * lda + ks0 * 8, ldsA + c0 * 512);
    gload_lds16(Ak + (size_t)(r01 + lane) * lda + ks1 * 8, ldsA + c1 * 512);
    gload_lds16(Bk + (size_t)(r00 + lane) * ldb + ks0 * 8, ldsB + c0 * 512);
    gload_lds16(Bk + (size_t)(r01 + lane) * ldb + ks1 * 8, ldsB + c1 * 512);
    __syncthreads();
    s16x8 af[4], bfr[4];
#pragma unroll
    for (int mi = 0; mi < 4; ++mi)
      af[mi] = *(const s16x8*)(ldsAc + offA + mi * 256);
#pragma unroll
    for (int ni = 0; ni < 4; ++ni)
      bfr[ni] = *(const s16x8*)(ldsBc + offB + ni * 256);
#pragma unroll
    for (int mi = 0; mi < 4; ++mi)
#pragma unroll
      for (int ni = 0; ni < 4; ++ni)
        acc[mi][ni] = __builtin_amdgcn_mfma_f32_16x16x32_bf16(
            af[mi], bfr[ni], acc[mi][ni], 0, 0, 0);
    __syncthreads();
  }
}

#define ZERO_ACC(acc)                                        \
  _Pragma("unroll") for (int za = 0; za < 4; ++za)           \
  _Pragma("unroll") for (int zb = 0; zb < 4; ++zb)           \
      acc[za][zb] = (f32x4){0.f, 0.f, 0.f, 0.f};

// ---------------------------------------------------------------------------
// prep: rope tables + x->bf16 + W->bf16 (one launch)
// ---------------------------------------------------------------------------
__global__ __launch_bounds__(256) void prep(
    const float* __restrict__ x, const float* __restrict__ W,
    unsigned short* __restrict__ xb, unsigned short* __restrict__ Wb,
    float* __restrict__ cosT, float* __restrict__ sinT)
{
  const int bid = blockIdx.x, tid = threadIdx.x;
  if (bid < 2048) {
    int idx = (bid * 256 + tid) * 8;
    f32x4 a = *(const f32x4*)(x + idx);
    f32x4 b = *(const f32x4*)(x + idx + 4);
    u16x8 o;
    o[0]=f2bf(a[0]); o[1]=f2bf(a[1]); o[2]=f2bf(a[2]); o[3]=f2bf(a[3]);
    o[4]=f2bf(b[0]); o[5]=f2bf(b[1]); o[6]=f2bf(b[2]); o[7]=f2bf(b[3]);
    *(u16x8*)(xb + idx) = o;
  } else if (bid < 2304) {
    int idx = ((bid - 2048) * 256 + tid) * 8;
    f32x4 a = *(const f32x4*)(W + idx);
    f32x4 b = *(const f32x4*)(W + idx + 4);
    u16x8 o;
    o[0]=f2bf(a[0]); o[1]=f2bf(a[1]); o[2]=f2bf(a[2]); o[3]=f2bf(a[3]);
    o[4]=f2bf(b[0]); o[5]=f2bf(b[1]); o[6]=f2bf(b[2]); o[7]=f2bf(b[3]);
    *(u16x8*)(Wb + idx) = o;
  } else {
    int idx = (bid - 2304) * 256 + tid;     // 512*256 entries
    int t = idx >> 8, i = idx & 255;
    float theta = expf(-9.210340371976184f * (float)(2 * i) * (1.0f / 512.0f));
    float s, c;
    sincosf((float)(t + 1) * theta, &s, &c);
    cosT[idx] = c;
    sinT[idx] = s;
  }
}

// ---------------------------------------------------------------------------
// GEMM1: qkv projection (q,k only). q pre-scaled by 1/sqrt(D). k gets RoPE.
// ---------------------------------------------------------------------------
__global__ __launch_bounds__(256) void gemm_qk(
    const unsigned short* __restrict__ xb, const unsigned short* __restrict__ Wb,
    const float* __restrict__ bias, const float* __restrict__ cosT,
    const float* __restrict__ sinT, unsigned short* __restrict__ qb,
    unsigned short* __restrict__ kb) {
  __shared__ __align__(16) unsigned short ldsA[4096];
  __shared__ __align__(16) unsigned short ldsB[4096];
  const int bm = blockIdx.x, bn = blockIdx.y;
  f32x4 acc[4][4];
  ZERO_ACC(acc);
  gemm_mainloop(xb + (size_t)bm * 128 * 512, Wb + (size_t)bn * 128 * 512,
                512, 512, 16, ldsA, ldsB, acc);
  const int lane = threadIdx.x & 63, wave = threadIdx.x >> 6;
  const int wr = wave >> 1, wc = wave & 1;
  const int rowbase = bm * 128 + wr * 64 + ((lane >> 4) << 2);
  const int colbase = bn * 128 + wc * 64 + (lane & 15);
  const bool isK = (bn >= 4);
#pragma unroll
  for (int ni = 0; ni < 4; ++ni) {
    const int col = colbase + ni * 16;
    const float bv = bias[col];
#pragma unroll
    for (int mi = 0; mi < 4; ++mi) {
#pragma unroll
      for (int r = 0; r < 4; ++r) {
        const int m = rowbase + mi * 16 + r;
        float v = acc[mi][ni][r] + bv;
        if (!isK) {
          qb[(size_t)m * 512 + col] = f2bf(v * SCALE_Q);
        } else {
          float p = __shfl_xor(v, 1);
          const int d = col - 512;
          const int t = m & 511;
          const float c = cosT[t * 256 + (d >> 1)];
          const float s = sinT[t * 256 + (d >> 1)];
          float o = (d & 1) ? (v * c - p * s) : (v * c + p * s);
          kb[(size_t)m * 512 + d] = f2bf(o);
        }
      }
    }
  }
}

// 32x32 tiled bf16 transpose per batch: krot[b][t][d] -> krotT[b][d][t]
__global__ void transpose_bf(const unsigned short* __restrict__ in,
                             unsigned short* __restrict__ out) {
  __shared__ unsigned short tile[32][33];
  const int b = blockIdx.z;
  const int t0 = blockIdx.x * 32, d0 = blockIdx.y * 32;
  const int x = threadIdx.x, y = threadIdx.y;
  const unsigned short* src = in + (size_t)b * 262144;
  unsigned short* dst = out + (size_t)b * 262144;
#pragma unroll
  for (int r = 0; r < 32; r += 8)
    tile[y + r][x] = src[(size_t)(t0 + y + r) * 512 + d0 + x];
  __syncthreads();
#pragma unroll
  for (int r = 0; r < 32; r += 8)
    dst[(size_t)(d0 + y + r) * 512 + t0 + x] = tile[x][y + r];
}

// ---------------------------------------------------------------------------
// Fused flash attention v3: 512 blocks (b, 32-row strip, d-half), 4 waves,
// j-tile 32, LDS 50.5KB -> 3 blocks/CU. Wave (wr,wc): QK quadrant
// rows wr*16, cols wc*16 (K=512, Q in regs); PV rows wr*16 x d wc*128.
// ---------------------------------------------------------------------------
#define ATT_LDS 51968

__global__ __launch_bounds__(256, 3) void fused_attn(
    const unsigned short* __restrict__ qb,   // [16][512][512] (scaled)
    const unsigned short* __restrict__ kb,   // [16][512][512] rotated k
    const unsigned short* __restrict__ kTb,  // [16][512][512] d-major
    float* __restrict__ out)                 // [16][512][512]
{
  extern __shared__ char smem[];
  unsigned short* krot_s = (unsigned short*)smem;            // [32][512] 32KB
  unsigned short* kT_s   = (unsigned short*)(smem + 32768);  // [256][32] 16KB
  char*           P_s    = smem + 49152;                     // [32][32]bf16 2KB
  float*          maxbuf = (float*)(smem + 51200);           // [32][2]
  float*          sumbuf = (float*)(smem + 51456);           // [32][2]

  const int tid = threadIdx.x;
  const int l   = tid & 63;
  const int w   = tid >> 6;
  const int l15 = l & 15, l4 = l >> 4;
  const int wr = w >> 1, wc = w & 1;

  const int t  = blockIdx.x;          // 512 tasks, heavy strips first
  const int s  = 15 - (t >> 5);
  const int b  = (t >> 1) & 15;
  const int dh = t & 1;
  const int nt = s + 1;               // j-tiles of 32

  // Q A-frags in regs: rows s*32 + wr*16 + l15, k = ks*32 + l4*8
  s16x8 qf[16];
  {
    const unsigned short* qbase =
        qb + ((size_t)b * 512 + s * 32 + wr * 16 + l15) * 512 + l4 * 8;
#pragma unroll
    for (int ks = 0; ks < 16; ++ks)
      qf[ks] = *(const s16x8*)(qbase + ks * 32);
  }

  f32x4 o[8];
#pragma unroll
  for (int i = 0; i < 8; ++i) o[i] = (f32x4){0.f, 0.f, 0.f, 0.f};
  float m_run[4], l_run[4];
#pragma unroll
  for (int r = 0; r < 4; ++r) { m_run[r] = -3.0e38f; l_run[r] = 0.f; }

  const unsigned short* kbb  = kb  + (size_t)b * 262144;
  const unsigned short* kTbb = kTb + (size_t)b * 262144 + (size_t)dh * 131072;

  for (int jt = 0; jt < nt; ++jt) {
    __syncthreads();   // prior tile's QK/PV reads complete before restage
    // ---- stage krot rows [32jt,+32) x K=512 (src pre-swizzled, rule #21) --
    {
      const unsigned short* src = kbb + (size_t)jt * 32 * 512;
#pragma unroll
      for (int c = 0; c < 8; ++c) {
        const int jl = w * 8 + c;
        const int colb = (l * 16) ^ ((jl & 7) << 4);
        gload_lds16(src + (size_t)jl * 512 + (colb >> 1), krot_s + jl * 512);
      }
      // kT window [256 d][32 j]; 64B rows, swz (dl&3)<<4
#pragma unroll
      for (int c = 0; c < 4; ++c) {
        const int dl = w * 64 + c * 16 + (l >> 2);
        const int colb = ((l & 3) * 16) ^ ((dl & 3) << 4);
        gload_lds16(kTbb + (size_t)dl * 512 + jt * 32 + (colb >> 1),
                    kT_s + (w * 64 + c * 16) * 32 + l * 8);
      }
    }
    __syncthreads();

    // ---- QK quadrant (rows wr, j-cols wc) ----
    f32x4 sf = (f32x4){0.f, 0.f, 0.f, 0.f};
    {
      const int jl = wc * 16 + l15;
      const char* kbase = (const char*)krot_s + jl * 1024;
      const int swz = (jl & 7) << 4;
#pragma unroll
      for (int ks = 0; ks < 16; ++ks) {
        s16x8 bf = *(const s16x8*)(kbase + ((ks * 64 + l4 * 16) ^ swz));
        sf = __builtin_amdgcn_mfma_f32_16x16x32_bf16(qf[ks], bf, sf, 0, 0, 0);
      }
    }
    if (jt == s) {                      // causal mask, only last tile
      const int jcol = jt * 32 + wc * 16 + l15;
#pragma unroll
      for (int r = 0; r < 4; ++r) {
        const int i = s * 32 + wr * 16 + l4 * 4 + r;
        if (jcol > i) sf[r] = -3.0e38f;
      }
    }
    float tm[4];
#pragma unroll
    for (int r = 0; r < 4; ++r) tm[r] = redmax16(sf[r]);
    if (l15 == 0) {
#pragma unroll
      for (int r = 0; r < 4; ++r)
        maxbuf[(wr * 16 + l4 * 4 + r) * 2 + wc] = tm[r];
    }
    __syncthreads();

    // ---- softmax (per-row stats from both wc halves) ----
    float scl[4], psum[4];
#pragma unroll
    for (int r = 0; r < 4; ++r) {
      const int row = wr * 16 + l4 * 4 + r;
      const float mnew =
          fmaxf(m_run[r], fmaxf(maxbuf[row * 2], maxbuf[row * 2 + 1]));
      scl[r] = __expf(m_run[r] - mnew);
      m_run[r] = mnew;
      const float p = __expf(sf[r] - mnew);
      sf[r] = p;
      psum[r] = redsum16(p);
    }
    {
      const int colb = (wc * 16 + l15) * 2;
#pragma unroll
      for (int r = 0; r < 4; ++r) {
        const int row = wr * 16 + l4 * 4 + r;
        *(unsigned short*)(P_s + row * 64 + (colb ^ ((row & 3) << 4))) =
            f2bf(sf[r]);
      }
    }
    if (l15 == 0) {
#pragma unroll
      for (int r = 0; r < 4; ++r)
        sumbuf[(wr * 16 + l4 * 4 + r) * 2 + wc] = psum[r];
    }
    __syncthreads();

    // ---- l update, O rescale, PV (rows wr, d-cols wc*128) ----
#pragma unroll
    for (int r = 0; r < 4; ++r) {
      const int row = wr * 16 + l4 * 4 + r;
      l_run[r] = l_run[r] * scl[r] + sumbuf[row * 2] + sumbuf[row * 2 + 1];
    }
#pragma unroll
    for (int df = 0; df < 8; ++df)
#pragma unroll
      for (int r = 0; r < 4; ++r)
        o[df][r] *= scl[r];
    {
      const int arow = wr * 16 + l15;
      s16x8 pa = *(const s16x8*)(P_s + arow * 64 +
                                 ((l4 * 16) ^ ((arow & 3) << 4)));
#pragma unroll
      for (int df = 0; df < 8; ++df) {
        const int dl = wc * 128 + df * 16 + l15;
        s16x8 vb = *(const s16x8*)((const char*)kT_s + dl * 64 +
                                   ((l4 * 16) ^ ((dl & 3) << 4)));
        o[df] = __builtin_amdgcn_mfma_f32_16x16x32_bf16(pa, vb, o[df], 0, 0, 0);
      }
    }
  }

  // ---- epilogue: O / l -> out ----
  float* ob = out + ((size_t)b * 512 + s * 32 + wr * 16) * 512 + dh * 256 + wc * 128;
#pragma unroll
  for (int r = 0; r < 4; ++r) {
    const float inv = 1.0f / l_run[r];
    const int row = l4 * 4 + r;
#pragma unroll
    for (int df = 0; df < 8; ++df)
      ob[(size_t)row * 512 + df * 16 + l15] = o[df][r] * inv;
  }
}

// ---------------------------------------------------------------------------
extern "C" void kernel_launch(void* const* d_in, const int* in_sizes, int n_in,
                              void* d_out, int out_size, void* d_ws, size_t ws_size,
                              hipStream_t stream) {
  (void)in_sizes; (void)n_in; (void)out_size; (void)ws_size;
  const float* x    = (const float*)d_in[0];   // [16,512,512]
  const float* W    = (const float*)d_in[1];   // [1536,512]
  const float* bias = (const float*)d_in[2];   // [1536]
  float* out = (float*)d_out;                  // [16,512,512]
  char* ws = (char*)d_ws;

  float* cosT            = (float*)(ws);                    // 512*256 f32
  float* sinT            = (float*)(ws + 524288);
  unsigned short* xb     = (unsigned short*)(ws + 1048576); // [8192,512] bf16
  unsigned short* Wb     = (unsigned short*)(ws + 9437184); // [1024,512] bf16
  unsigned short* qb     = (unsigned short*)(ws + 10485760);// [16,512,512] bf16 (scaled)
  unsigned short* kb     = (unsigned short*)(ws + 18874368);// krot
  unsigned short* kTb    = (unsigned short*)(ws + 27262976);// krot^T

  prep<<<2816, 256, 0, stream>>>(x, W, xb, Wb, cosT, sinT);
  gemm_qk<<<dim3(64, 8), 256, 0, stream>>>(xb, Wb, bias, cosT, sinT, qb, kb);
  transpose_bf<<<dim3(16, 16, 16), dim3(32, 8), 0, stream>>>(kb, kTb);
  fused_attn<<<512, 256, ATT_LDS, stream>>>(qb, kb, kTb, out);
}

// Round 4
// 90.681 us; speedup vs baseline: 1.3331x; 1.3331x over previous
//
#include <hip/hip_runtime.h>
#include <hip/hip_bf16.h>

typedef float  f32x4  __attribute__((ext_vector_type(4)));
typedef short  s16x8  __attribute__((ext_vector_type(8)));
typedef unsigned short u16x8 __attribute__((ext_vector_type(8)));

#define T_  512
#define D_  512
#define BTD 4194304   // 16*512*512
#define SCALE_Q 0.044194173824159216f   // 1/sqrt(512)

static __device__ __forceinline__ unsigned short f2bf(float f) {
  unsigned u = __builtin_bit_cast(unsigned, f);
  u += 0x7fffu + ((u >> 16) & 1u);
  return (unsigned short)(u >> 16);
}

static __device__ __forceinline__ void gload_lds16(const void* g, void* l) {
  __builtin_amdgcn_global_load_lds(
      (__attribute__((address_space(1))) void*)(g),
      (__attribute__((address_space(3))) void*)(l),
      16, 0, 0);
}

static __device__ __forceinline__ float redmax16(float v) {
  v = fmaxf(v, __shfl_xor(v, 1)); v = fmaxf(v, __shfl_xor(v, 2));
  v = fmaxf(v, __shfl_xor(v, 4)); v = fmaxf(v, __shfl_xor(v, 8));
  return v;
}
static __device__ __forceinline__ float redsum16(float v) {
  v += __shfl_xor(v, 1); v += __shfl_xor(v, 2);
  v += __shfl_xor(v, 4); v += __shfl_xor(v, 8);
  return v;
}

// ---------------------------------------------------------------------------
// 128x128-tile bt-GEMM mainloop (proven): C += A[M,K] * B[N,K]^T.
// ---------------------------------------------------------------------------
__device__ __forceinline__ void gemm_mainloop(
    const unsigned short* __restrict__ A,
    const unsigned short* __restrict__ B,
    int lda, int ldb, int ksteps,
    unsigned short* ldsA, unsigned short* ldsB,
    f32x4 acc[4][4])
{
  const int tid  = threadIdx.x;
  const int lane = tid & 63;
  const int wave = tid >> 6;
  const int wr = wave >> 1, wc = wave & 1;

  const int c0 = wave, c1 = wave + 4;
  const int ks0 = c0 >> 1, r00 = (c0 & 1) * 64;
  const int ks1 = c1 >> 1, r01 = (c1 & 1) * 64;

  const char* ldsAc = (const char*)ldsA;
  const char* ldsBc = (const char*)ldsB;
  const int offA = (lane >> 4) * 2048 + (wr * 64 + (lane & 15)) * 16;
  const int offB = (lane >> 4) * 2048 + (wc * 64 + (lane & 15)) * 16;

  for (int kt = 0; kt < ksteps; ++kt) {
    const unsigned short* Ak = A + kt * 32;
    const unsigned short* Bk = B + kt * 32;
    gload_lds16(Ak + (size_t)(r00 + lane) * lda + ks0 * 8, ldsA + c0 * 512);
    gload_lds16(Ak + (size_t)(r01 + lane) * lda + ks1 * 8, ldsA + c1 * 512);
    gload_lds16(Bk + (size_t)(r00 + lane) * ldb + ks0 * 8, ldsB + c0 * 512);
    gload_lds16(Bk + (size_t)(r01 + lane) * ldb + ks1 * 8, ldsB + c1 * 512);
    __syncthreads();
    s16x8 af[4], bfr[4];
#pragma unroll
    for (int mi = 0; mi < 4; ++mi)
      af[mi] = *(const s16x8*)(ldsAc + offA + mi * 256);
#pragma unroll
    for (int ni = 0; ni < 4; ++ni)
      bfr[ni] = *(const s16x8*)(ldsBc + offB + ni * 256);
#pragma unroll
    for (int mi = 0; mi < 4; ++mi)
#pragma unroll
      for (int ni = 0; ni < 4; ++ni)
        acc[mi][ni] = __builtin_amdgcn_mfma_f32_16x16x32_bf16(
            af[mi], bfr[ni], acc[mi][ni], 0, 0, 0);
    __syncthreads();
  }
}

#define ZERO_ACC(acc)                                        \
  _Pragma("unroll") for (int za = 0; za < 4; ++za)           \
  _Pragma("unroll") for (int zb = 0; zb < 4; ++zb)           \
      acc[za][zb] = (f32x4){0.f, 0.f, 0.f, 0.f};

// ---------------------------------------------------------------------------
// prep: rope tables + x->bf16 + W->bf16 (one launch)
// ---------------------------------------------------------------------------
__global__ __launch_bounds__(256) void prep(
    const float* __restrict__ x, const float* __restrict__ W,
    unsigned short* __restrict__ xb, unsigned short* __restrict__ Wb,
    float* __restrict__ cosT, float* __restrict__ sinT)
{
  const int bid = blockIdx.x, tid = threadIdx.x;
  if (bid < 2048) {
    int idx = (bid * 256 + tid) * 8;
    f32x4 a = *(const f32x4*)(x + idx);
    f32x4 b = *(const f32x4*)(x + idx + 4);
    u16x8 o;
    o[0]=f2bf(a[0]); o[1]=f2bf(a[1]); o[2]=f2bf(a[2]); o[3]=f2bf(a[3]);
    o[4]=f2bf(b[0]); o[5]=f2bf(b[1]); o[6]=f2bf(b[2]); o[7]=f2bf(b[3]);
    *(u16x8*)(xb + idx) = o;
  } else if (bid < 2304) {
    int idx = ((bid - 2048) * 256 + tid) * 8;
    f32x4 a = *(const f32x4*)(W + idx);
    f32x4 b = *(const f32x4*)(W + idx + 4);
    u16x8 o;
    o[0]=f2bf(a[0]); o[1]=f2bf(a[1]); o[2]=f2bf(a[2]); o[3]=f2bf(a[3]);
    o[4]=f2bf(b[0]); o[5]=f2bf(b[1]); o[6]=f2bf(b[2]); o[7]=f2bf(b[3]);
    *(u16x8*)(Wb + idx) = o;
  } else {
    int idx = (bid - 2304) * 256 + tid;     // 512*256 entries
    int t = idx >> 8, i = idx & 255;
    float theta = expf(-9.210340371976184f * (float)(2 * i) * (1.0f / 512.0f));
    float s, c;
    sincosf((float)(t + 1) * theta, &s, &c);
    cosT[idx] = c;
    sinT[idx] = s;
  }
}

// ---------------------------------------------------------------------------
// GEMM1: qkv projection (q,k only). q pre-scaled by 1/sqrt(D). k gets RoPE.
// ---------------------------------------------------------------------------
__global__ __launch_bounds__(256) void gemm_qk(
    const unsigned short* __restrict__ xb, const unsigned short* __restrict__ Wb,
    const float* __restrict__ bias, const float* __restrict__ cosT,
    const float* __restrict__ sinT, unsigned short* __restrict__ qb,
    unsigned short* __restrict__ kb) {
  __shared__ __align__(16) unsigned short ldsA[4096];
  __shared__ __align__(16) unsigned short ldsB[4096];
  const int bm = blockIdx.x, bn = blockIdx.y;
  f32x4 acc[4][4];
  ZERO_ACC(acc);
  gemm_mainloop(xb + (size_t)bm * 128 * 512, Wb + (size_t)bn * 128 * 512,
                512, 512, 16, ldsA, ldsB, acc);
  const int lane = threadIdx.x & 63, wave = threadIdx.x >> 6;
  const int wr = wave >> 1, wc = wave & 1;
  const int rowbase = bm * 128 + wr * 64 + ((lane >> 4) << 2);
  const int colbase = bn * 128 + wc * 64 + (lane & 15);
  const bool isK = (bn >= 4);
#pragma unroll
  for (int ni = 0; ni < 4; ++ni) {
    const int col = colbase + ni * 16;
    const float bv = bias[col];
#pragma unroll
    for (int mi = 0; mi < 4; ++mi) {
#pragma unroll
      for (int r = 0; r < 4; ++r) {
        const int m = rowbase + mi * 16 + r;
        float v = acc[mi][ni][r] + bv;
        if (!isK) {
          qb[(size_t)m * 512 + col] = f2bf(v * SCALE_Q);
        } else {
          float p = __shfl_xor(v, 1);
          const int d = col - 512;
          const int t = m & 511;
          const float c = cosT[t * 256 + (d >> 1)];
          const float s = sinT[t * 256 + (d >> 1)];
          float o = (d & 1) ? (v * c - p * s) : (v * c + p * s);
          kb[(size_t)m * 512 + d] = f2bf(o);
        }
      }
    }
  }
}

// 32x32 tiled bf16 transpose per batch: krot[b][t][d] -> krotT[b][d][t]
__global__ void transpose_bf(const unsigned short* __restrict__ in,
                             unsigned short* __restrict__ out) {
  __shared__ unsigned short tile[32][33];
  const int b = blockIdx.z;
  const int t0 = blockIdx.x * 32, d0 = blockIdx.y * 32;
  const int x = threadIdx.x, y = threadIdx.y;
  const unsigned short* src = in + (size_t)b * 262144;
  unsigned short* dst = out + (size_t)b * 262144;
#pragma unroll
  for (int r = 0; r < 32; r += 8)
    tile[y + r][x] = src[(size_t)(t0 + y + r) * 512 + d0 + x];
  __syncthreads();
#pragma unroll
  for (int r = 0; r < 32; r += 8)
    dst[(size_t)(d0 + y + r) * 512 + t0 + x] = tile[x][y + r];
}

// ---------------------------------------------------------------------------
// Fused flash attention v4: 512 blocks, 4 waves, j-tile 32, LDS 50.5KB.
// v3 spill fix: launch_bounds (256,2) — natural VGPR alloc (~150-170), no
// scratch. XCD-aware remap: xcd = blockIdx&7 owns batches {2*xcd, 2*xcd+1}
// so each XCD's k/kT working set (~3MB) fits its private 4MB L2.
// ---------------------------------------------------------------------------
#define ATT_LDS 51968

__global__ __launch_bounds__(256, 2) void fused_attn(
    const unsigned short* __restrict__ qb,   // [16][512][512] (scaled)
    const unsigned short* __restrict__ kb,   // [16][512][512] rotated k
    const unsigned short* __restrict__ kTb,  // [16][512][512] d-major
    float* __restrict__ out)                 // [16][512][512]
{
  extern __shared__ char smem[];
  unsigned short* krot_s = (unsigned short*)smem;            // [32][512] 32KB
  unsigned short* kT_s   = (unsigned short*)(smem + 32768);  // [256][32] 16KB
  char*           P_s    = smem + 49152;                     // [32][32]bf16 2KB
  float*          maxbuf = (float*)(smem + 51200);           // [32][2]
  float*          sumbuf = (float*)(smem + 51456);           // [32][2]

  const int tid = threadIdx.x;
  const int l   = tid & 63;
  const int w   = tid >> 6;
  const int l15 = l & 15, l4 = l >> 4;
  const int wr = w >> 1, wc = w & 1;

  // XCD-aware task decode: 512 = 8 XCDs x 64 slots, bijective.
  const int xcd  = blockIdx.x & 7;
  const int slot = blockIdx.x >> 3;          // 0..63
  const int b    = xcd * 2 + (slot & 1);     // 2 batches per XCD
  const int dh   = (slot >> 1) & 1;
  const int s    = 15 - (slot >> 2);         // heavy strips dispatched first
  const int nt   = s + 1;                    // j-tiles of 32

  // Q A-frags in regs: rows s*32 + wr*16 + l15, k = ks*32 + l4*8
  s16x8 qf[16];
  {
    const unsigned short* qbase =
        qb + ((size_t)b * 512 + s * 32 + wr * 16 + l15) * 512 + l4 * 8;
#pragma unroll
    for (int ks = 0; ks < 16; ++ks)
      qf[ks] = *(const s16x8*)(qbase + ks * 32);
  }

  f32x4 o[8];
#pragma unroll
  for (int i = 0; i < 8; ++i) o[i] = (f32x4){0.f, 0.f, 0.f, 0.f};
  float m_run[4], l_run[4];
#pragma unroll
  for (int r = 0; r < 4; ++r) { m_run[r] = -3.0e38f; l_run[r] = 0.f; }

  const unsigned short* kbb  = kb  + (size_t)b * 262144;
  const unsigned short* kTbb = kTb + (size_t)b * 262144 + (size_t)dh * 131072;

  for (int jt = 0; jt < nt; ++jt) {
    __syncthreads();   // prior tile's QK/PV reads complete before restage
    // ---- stage krot rows [32jt,+32) x K=512 (src pre-swizzled, rule #21) --
    {
      const unsigned short* src = kbb + (size_t)jt * 32 * 512;
#pragma unroll
      for (int c = 0; c < 8; ++c) {
        const int jl = w * 8 + c;
        const int colb = (l * 16) ^ ((jl & 7) << 4);
        gload_lds16(src + (size_t)jl * 512 + (colb >> 1), krot_s + jl * 512);
      }
      // kT window [256 d][32 j]; 64B rows, swz (dl&3)<<4
#pragma unroll
      for (int c = 0; c < 4; ++c) {
        const int dl = w * 64 + c * 16 + (l >> 2);
        const int colb = ((l & 3) * 16) ^ ((dl & 3) << 4);
        gload_lds16(kTbb + (size_t)dl * 512 + jt * 32 + (colb >> 1),
                    kT_s + (w * 64 + c * 16) * 32 + l * 8);
      }
    }
    __syncthreads();

    // ---- QK quadrant (rows wr, j-cols wc) ----
    f32x4 sf = (f32x4){0.f, 0.f, 0.f, 0.f};
    {
      const int jl = wc * 16 + l15;
      const char* kbase = (const char*)krot_s + jl * 1024;
      const int swz = (jl & 7) << 4;
#pragma unroll
      for (int ks = 0; ks < 16; ++ks) {
        s16x8 bf = *(const s16x8*)(kbase + ((ks * 64 + l4 * 16) ^ swz));
        sf = __builtin_amdgcn_mfma_f32_16x16x32_bf16(qf[ks], bf, sf, 0, 0, 0);
      }
    }
    if (jt == s) {                      // causal mask, only last tile
      const int jcol = jt * 32 + wc * 16 + l15;
#pragma unroll
      for (int r = 0; r < 4; ++r) {
        const int i = s * 32 + wr * 16 + l4 * 4 + r;
        if (jcol > i) sf[r] = -3.0e38f;
      }
    }
    float tm[4];
#pragma unroll
    for (int r = 0; r < 4; ++r) tm[r] = redmax16(sf[r]);
    if (l15 == 0) {
#pragma unroll
      for (int r = 0; r < 4; ++r)
        maxbuf[(wr * 16 + l4 * 4 + r) * 2 + wc] = tm[r];
    }
    __syncthreads();

    // ---- softmax (per-row stats from both wc halves) ----
    float scl[4], psum[4];
#pragma unroll
    for (int r = 0; r < 4; ++r) {
      const int row = wr * 16 + l4 * 4 + r;
      const float mnew =
          fmaxf(m_run[r], fmaxf(maxbuf[row * 2], maxbuf[row * 2 + 1]));
      scl[r] = __expf(m_run[r] - mnew);
      m_run[r] = mnew;
      const float p = __expf(sf[r] - mnew);
      sf[r] = p;
      psum[r] = redsum16(p);
    }
    {
      const int colb = (wc * 16 + l15) * 2;
#pragma unroll
      for (int r = 0; r < 4; ++r) {
        const int row = wr * 16 + l4 * 4 + r;
        *(unsigned short*)(P_s + row * 64 + (colb ^ ((row & 3) << 4))) =
            f2bf(sf[r]);
      }
    }
    if (l15 == 0) {
#pragma unroll
      for (int r = 0; r < 4; ++r)
        sumbuf[(wr * 16 + l4 * 4 + r) * 2 + wc] = psum[r];
    }
    __syncthreads();

    // ---- l update, O rescale, PV (rows wr, d-cols wc*128) ----
#pragma unroll
    for (int r = 0; r < 4; ++r) {
      const int row = wr * 16 + l4 * 4 + r;
      l_run[r] = l_run[r] * scl[r] + sumbuf[row * 2] + sumbuf[row * 2 + 1];
    }
#pragma unroll
    for (int df = 0; df < 8; ++df)
#pragma unroll
      for (int r = 0; r < 4; ++r)
        o[df][r] *= scl[r];
    {
      const int arow = wr * 16 + l15;
      s16x8 pa = *(const s16x8*)(P_s + arow * 64 +
                                 ((l4 * 16) ^ ((arow & 3) << 4)));
#pragma unroll
      for (int df = 0; df < 8; ++df) {
        const int dl = wc * 128 + df * 16 + l15;
        s16x8 vb = *(const s16x8*)((const char*)kT_s + dl * 64 +
                                   ((l4 * 16) ^ ((dl & 3) << 4)));
        o[df] = __builtin_amdgcn_mfma_f32_16x16x32_bf16(pa, vb, o[df], 0, 0, 0);
      }
    }
  }

  // ---- epilogue: O / l -> out ----
  float* ob = out + ((size_t)b * 512 + s * 32 + wr * 16) * 512 + dh * 256 + wc * 128;
#pragma unroll
  for (int r = 0; r < 4; ++r) {
    const float inv = 1.0f / l_run[r];
    const int row = l4 * 4 + r;
#pragma unroll
    for (int df = 0; df < 8; ++df)
      ob[(size_t)row * 512 + df * 16 + l15] = o[df][r] * inv;
  }
}

// ---------------------------------------------------------------------------
extern "C" void kernel_launch(void* const* d_in, const int* in_sizes, int n_in,
                              void* d_out, int out_size, void* d_ws, size_t ws_size,
                              hipStream_t stream) {
  (void)in_sizes; (void)n_in; (void)out_size; (void)ws_size;
  const float* x    = (const float*)d_in[0];   // [16,512,512]
  const float* W    = (const float*)d_in[1];   // [1536,512]
  const float* bias = (const float*)d_in[2];   // [1536]
  float* out = (float*)d_out;                  // [16,512,512]
  char* ws = (char*)d_ws;

  float* cosT            = (float*)(ws);                    // 512*256 f32
  float* sinT            = (float*)(ws + 524288);
  unsigned short* xb     = (unsigned short*)(ws + 1048576); // [8192,512] bf16
  unsigned short* Wb     = (unsigned short*)(ws + 9437184); // [1024,512] bf16
  unsigned short* qb     = (unsigned short*)(ws + 10485760);// [16,512,512] bf16 (scaled)
  unsigned short* kb     = (unsigned short*)(ws + 18874368);// krot
  unsigned short* kTb    = (unsigned short*)(ws + 27262976);// krot^T

  prep<<<2816, 256, 0, stream>>>(x, W, xb, Wb, cosT, sinT);
  gemm_qk<<<dim3(64, 8), 256, 0, stream>>>(xb, Wb, bias, cosT, sinT, qb, kb);
  transpose_bf<<<dim3(16, 16, 16), dim3(32, 8), 0, stream>>>(kb, kTb);
  fused_attn<<<512, 256, ATT_LDS, stream>>>(qb, kb, kTb, out);
}

// Round 5
// 84.522 us; speedup vs baseline: 1.4303x; 1.0729x over previous
//
#include <hip/hip_runtime.h>
#include <hip/hip_bf16.h>

typedef float  f32x4  __attribute__((ext_vector_type(4)));
typedef short  s16x8  __attribute__((ext_vector_type(8)));
typedef unsigned short u16x8 __attribute__((ext_vector_type(8)));

#define T_  512
#define D_  512
#define BTD 4194304   // 16*512*512
#define SCALE_Q 0.044194173824159216f   // 1/sqrt(512)

static __device__ __forceinline__ unsigned short f2bf(float f) {
  unsigned u = __builtin_bit_cast(unsigned, f);
  u += 0x7fffu + ((u >> 16) & 1u);
  return (unsigned short)(u >> 16);
}

static __device__ __forceinline__ void gload_lds16(const void* g, void* l) {
  __builtin_amdgcn_global_load_lds(
      (__attribute__((address_space(1))) void*)(g),
      (__attribute__((address_space(3))) void*)(l),
      16, 0, 0);
}

static __device__ __forceinline__ float redmax16(float v) {
  v = fmaxf(v, __shfl_xor(v, 1)); v = fmaxf(v, __shfl_xor(v, 2));
  v = fmaxf(v, __shfl_xor(v, 4)); v = fmaxf(v, __shfl_xor(v, 8));
  return v;
}
static __device__ __forceinline__ float redsum16(float v) {
  v += __shfl_xor(v, 1); v += __shfl_xor(v, 2);
  v += __shfl_xor(v, 4); v += __shfl_xor(v, 8);
  return v;
}

// ---------------------------------------------------------------------------
// 128x128-tile bt-GEMM mainloop (proven): C += A[M,K] * B[N,K]^T.
// ---------------------------------------------------------------------------
__device__ __forceinline__ void gemm_mainloop(
    const unsigned short* __restrict__ A,
    const unsigned short* __restrict__ B,
    int lda, int ldb, int ksteps,
    unsigned short* ldsA, unsigned short* ldsB,
    f32x4 acc[4][4])
{
  const int tid  = threadIdx.x;
  const int lane = tid & 63;
  const int wave = tid >> 6;
  const int wr = wave >> 1, wc = wave & 1;

  const int c0 = wave, c1 = wave + 4;
  const int ks0 = c0 >> 1, r00 = (c0 & 1) * 64;
  const int ks1 = c1 >> 1, r01 = (c1 & 1) * 64;

  const char* ldsAc = (const char*)ldsA;
  const char* ldsBc = (const char*)ldsB;
  const int offA = (lane >> 4) * 2048 + (wr * 64 + (lane & 15)) * 16;
  const int offB = (lane >> 4) * 2048 + (wc * 64 + (lane & 15)) * 16;

  for (int kt = 0; kt < ksteps; ++kt) {
    const unsigned short* Ak = A + kt * 32;
    const unsigned short* Bk = B + kt * 32;
    gload_lds16(Ak + (size_t)(r00 + lane) * lda + ks0 * 8, ldsA + c0 * 512);
    gload_lds16(Ak + (size_t)(r01 + lane) * lda + ks1 * 8, ldsA + c1 * 512);
    gload_lds16(Bk + (size_t)(r00 + lane) * ldb + ks0 * 8, ldsB + c0 * 512);
    gload_lds16(Bk + (size_t)(r01 + lane) * ldb + ks1 * 8, ldsB + c1 * 512);
    __syncthreads();
    s16x8 af[4], bfr[4];
#pragma unroll
    for (int mi = 0; mi < 4; ++mi)
      af[mi] = *(const s16x8*)(ldsAc + offA + mi * 256);
#pragma unroll
    for (int ni = 0; ni < 4; ++ni)
      bfr[ni] = *(const s16x8*)(ldsBc + offB + ni * 256);
#pragma unroll
    for (int mi = 0; mi < 4; ++mi)
#pragma unroll
      for (int ni = 0; ni < 4; ++ni)
        acc[mi][ni] = __builtin_amdgcn_mfma_f32_16x16x32_bf16(
            af[mi], bfr[ni], acc[mi][ni], 0, 0, 0);
    __syncthreads();
  }
}

#define ZERO_ACC(acc)                                        \
  _Pragma("unroll") for (int za = 0; za < 4; ++za)           \
  _Pragma("unroll") for (int zb = 0; zb < 4; ++zb)           \
      acc[za][zb] = (f32x4){0.f, 0.f, 0.f, 0.f};

// ---------------------------------------------------------------------------
// prep: rope tables + x->bf16 + W->bf16 (one launch)
// ---------------------------------------------------------------------------
__global__ __launch_bounds__(256) void prep(
    const float* __restrict__ x, const float* __restrict__ W,
    unsigned short* __restrict__ xb, unsigned short* __restrict__ Wb,
    float* __restrict__ cosT, float* __restrict__ sinT)
{
  const int bid = blockIdx.x, tid = threadIdx.x;
  if (bid < 2048) {
    int idx = (bid * 256 + tid) * 8;
    f32x4 a = *(const f32x4*)(x + idx);
    f32x4 b = *(const f32x4*)(x + idx + 4);
    u16x8 o;
    o[0]=f2bf(a[0]); o[1]=f2bf(a[1]); o[2]=f2bf(a[2]); o[3]=f2bf(a[3]);
    o[4]=f2bf(b[0]); o[5]=f2bf(b[1]); o[6]=f2bf(b[2]); o[7]=f2bf(b[3]);
    *(u16x8*)(xb + idx) = o;
  } else if (bid < 2304) {
    int idx = ((bid - 2048) * 256 + tid) * 8;
    f32x4 a = *(const f32x4*)(W + idx);
    f32x4 b = *(const f32x4*)(W + idx + 4);
    u16x8 o;
    o[0]=f2bf(a[0]); o[1]=f2bf(a[1]); o[2]=f2bf(a[2]); o[3]=f2bf(a[3]);
    o[4]=f2bf(b[0]); o[5]=f2bf(b[1]); o[6]=f2bf(b[2]); o[7]=f2bf(b[3]);
    *(u16x8*)(Wb + idx) = o;
  } else {
    int idx = (bid - 2304) * 256 + tid;     // 512*256 entries
    int t = idx >> 8, i = idx & 255;
    float theta = expf(-9.210340371976184f * (float)(2 * i) * (1.0f / 512.0f));
    float s, c;
    sincosf((float)(t + 1) * theta, &s, &c);
    cosT[idx] = c;
    sinT[idx] = s;
  }
}

// ---------------------------------------------------------------------------
// GEMM1: qkv projection (q,k only). q pre-scaled by 1/sqrt(D). k gets RoPE.
// ---------------------------------------------------------------------------
__global__ __launch_bounds__(256) void gemm_qk(
    const unsigned short* __restrict__ xb, const unsigned short* __restrict__ Wb,
    const float* __restrict__ bias, const float* __restrict__ cosT,
    const float* __restrict__ sinT, unsigned short* __restrict__ qb,
    unsigned short* __restrict__ kb) {
  __shared__ __align__(16) unsigned short ldsA[4096];
  __shared__ __align__(16) unsigned short ldsB[4096];
  const int bm = blockIdx.x, bn = blockIdx.y;
  f32x4 acc[4][4];
  ZERO_ACC(acc);
  gemm_mainloop(xb + (size_t)bm * 128 * 512, Wb + (size_t)bn * 128 * 512,
                512, 512, 16, ldsA, ldsB, acc);
  const int lane = threadIdx.x & 63, wave = threadIdx.x >> 6;
  const int wr = wave >> 1, wc = wave & 1;
  const int rowbase = bm * 128 + wr * 64 + ((lane >> 4) << 2);
  const int colbase = bn * 128 + wc * 64 + (lane & 15);
  const bool isK = (bn >= 4);
#pragma unroll
  for (int ni = 0; ni < 4; ++ni) {
    const int col = colbase + ni * 16;
    const float bv = bias[col];
#pragma unroll
    for (int mi = 0; mi < 4; ++mi) {
#pragma unroll
      for (int r = 0; r < 4; ++r) {
        const int m = rowbase + mi * 16 + r;
        float v = acc[mi][ni][r] + bv;
        if (!isK) {
          qb[(size_t)m * 512 + col] = f2bf(v * SCALE_Q);
        } else {
          float p = __shfl_xor(v, 1);
          const int d = col - 512;
          const int t = m & 511;
          const float c = cosT[t * 256 + (d >> 1)];
          const float s = sinT[t * 256 + (d >> 1)];
          float o = (d & 1) ? (v * c - p * s) : (v * c + p * s);
          kb[(size_t)m * 512 + d] = f2bf(o);
        }
      }
    }
  }
}

// 32x32 tiled bf16 transpose per batch: krot[b][t][d] -> krotT[b][d][t]
__global__ void transpose_bf(const unsigned short* __restrict__ in,
                             unsigned short* __restrict__ out) {
  __shared__ unsigned short tile[32][33];
  const int b = blockIdx.z;
  const int t0 = blockIdx.x * 32, d0 = blockIdx.y * 32;
  const int x = threadIdx.x, y = threadIdx.y;
  const unsigned short* src = in + (size_t)b * 262144;
  unsigned short* dst = out + (size_t)b * 262144;
#pragma unroll
  for (int r = 0; r < 32; r += 8)
    tile[y + r][x] = src[(size_t)(t0 + y + r) * 512 + d0 + x];
  __syncthreads();
#pragma unroll
  for (int r = 0; r < 32; r += 8)
    dst[(size_t)(d0 + y + r) * 512 + t0 + x] = tile[x][y + r];
}

// ---------------------------------------------------------------------------
// Fused flash attention v5: software-pipelined stage.
// Per tile: [A: sync+vmcnt drain] QK -> [B] softmax/P -> [C] -> issue
// stage(t+1) (krot + kT double-buffer) -> PV(t) overlaps the loads.
// 3 barriers/tile (was 4), stage latency hidden under PV.
// LDS 68.1KB -> 2 blocks/CU. XCD-aware decode: xcd owns 2 batches.
// ---------------------------------------------------------------------------
#define ATT_LDS 68096

__global__ __launch_bounds__(256, 2) void fused_attn(
    const unsigned short* __restrict__ qb,   // [16][512][512] (scaled)
    const unsigned short* __restrict__ kb,   // [16][512][512] rotated k
    const unsigned short* __restrict__ kTb,  // [16][512][512] d-major
    float* __restrict__ out)                 // [16][512][512]
{
  extern __shared__ char smem[];
  unsigned short* krot_s = (unsigned short*)smem;            // [32][512] 32KB
  unsigned short* kT_s   = (unsigned short*)(smem + 32768);  // 2x[256][32] 32KB
  char*           P_s    = smem + 65536;                     // [32][32]bf16 2KB
  float*          maxbuf = (float*)(smem + 67584);           // [32][2]
  float*          sumbuf = (float*)(smem + 67840);           // [32][2]

  const int tid = threadIdx.x;
  const int l   = tid & 63;
  const int w   = tid >> 6;
  const int l15 = l & 15, l4 = l >> 4;
  const int wr = w >> 1, wc = w & 1;

  // XCD-aware task decode: 512 = 8 XCDs x 64 slots, bijective.
  const int xcd  = blockIdx.x & 7;
  const int slot = blockIdx.x >> 3;          // 0..63
  const int b    = xcd * 2 + (slot & 1);     // 2 batches per XCD
  const int dh   = (slot >> 1) & 1;
  const int s    = 15 - (slot >> 2);         // heavy strips dispatched first
  const int nt   = s + 1;                    // j-tiles of 32

  // Q A-frags in regs: rows s*32 + wr*16 + l15, k = ks*32 + l4*8
  s16x8 qf[16];
  {
    const unsigned short* qbase =
        qb + ((size_t)b * 512 + s * 32 + wr * 16 + l15) * 512 + l4 * 8;
#pragma unroll
    for (int ks = 0; ks < 16; ++ks)
      qf[ks] = *(const s16x8*)(qbase + ks * 32);
  }

  f32x4 o[8];
#pragma unroll
  for (int i = 0; i < 8; ++i) o[i] = (f32x4){0.f, 0.f, 0.f, 0.f};
  float m_run[4], l_run[4];
#pragma unroll
  for (int r = 0; r < 4; ++r) { m_run[r] = -3.0e38f; l_run[r] = 0.f; }

  const unsigned short* kbb  = kb  + (size_t)b * 262144;
  const unsigned short* kTbb = kTb + (size_t)b * 262144 + (size_t)dh * 131072;

  // stage j-tile jt: krot rows [32jt,+32) x K=512, kT window into buf jt&1.
  // Sources pre-swizzled (rule #21).
  auto stage = [&](int jt) {
    const unsigned short* src = kbb + (size_t)jt * 32 * 512;
#pragma unroll
    for (int c = 0; c < 8; ++c) {
      const int jl = w * 8 + c;
      const int colb = (l * 16) ^ ((jl & 7) << 4);
      gload_lds16(src + (size_t)jl * 512 + (colb >> 1), krot_s + jl * 512);
    }
    unsigned short* kTd = kT_s + (jt & 1) * 8192;
#pragma unroll
    for (int c = 0; c < 4; ++c) {
      const int dl = w * 64 + c * 16 + (l >> 2);
      const int colb = ((l & 3) * 16) ^ ((dl & 3) << 4);
      gload_lds16(kTbb + (size_t)dl * 512 + jt * 32 + (colb >> 1),
                  kTd + (w * 64 + c * 16) * 32 + l * 8);
    }
  };

  stage(0);
  __syncthreads();                       // prologue drain

  for (int jt = 0; jt < nt; ++jt) {
    if (jt > 0) __syncthreads();         // A: drains stage(jt), post-PV(jt-1)

    // ---- QK quadrant (rows wr, j-cols wc), 2 interleaved acc chains ----
    f32x4 s0 = (f32x4){0.f, 0.f, 0.f, 0.f};
    f32x4 s1 = (f32x4){0.f, 0.f, 0.f, 0.f};
    {
      const int jl = wc * 16 + l15;
      const char* kbase = (const char*)krot_s + jl * 1024;
      const int swz = (jl & 7) << 4;
#pragma unroll
      for (int ks = 0; ks < 16; ks += 2) {
        s16x8 b0 = *(const s16x8*)(kbase + ((ks * 64 + l4 * 16) ^ swz));
        s16x8 b1 = *(const s16x8*)(kbase + (((ks + 1) * 64 + l4 * 16) ^ swz));
        s0 = __builtin_amdgcn_mfma_f32_16x16x32_bf16(qf[ks], b0, s0, 0, 0, 0);
        s1 = __builtin_amdgcn_mfma_f32_16x16x32_bf16(qf[ks + 1], b1, s1, 0, 0, 0);
      }
    }
    f32x4 sf = s0 + s1;
    if (jt == s) {                      // causal mask, only last tile
      const int jcol = jt * 32 + wc * 16 + l15;
#pragma unroll
      for (int r = 0; r < 4; ++r) {
        const int i = s * 32 + wr * 16 + l4 * 4 + r;
        if (jcol > i) sf[r] = -3.0e38f;
      }
    }
    float tm[4];
#pragma unroll
    for (int r = 0; r < 4; ++r) tm[r] = redmax16(sf[r]);
    if (l15 == 0) {
#pragma unroll
      for (int r = 0; r < 4; ++r)
        maxbuf[(wr * 16 + l4 * 4 + r) * 2 + wc] = tm[r];
    }
    __syncthreads();                     // B

    // ---- softmax (per-row stats from both wc halves) ----
    float scl[4], psum[4];
#pragma unroll
    for (int r = 0; r < 4; ++r) {
      const int row = wr * 16 + l4 * 4 + r;
      const float mnew =
          fmaxf(m_run[r], fmaxf(maxbuf[row * 2], maxbuf[row * 2 + 1]));
      scl[r] = __expf(m_run[r] - mnew);
      m_run[r] = mnew;
      const float p = __expf(sf[r] - mnew);
      sf[r] = p;
      psum[r] = redsum16(p);
    }
    {
      const int colb = (wc * 16 + l15) * 2;
#pragma unroll
      for (int r = 0; r < 4; ++r) {
        const int row = wr * 16 + l4 * 4 + r;
        *(unsigned short*)(P_s + row * 64 + (colb ^ ((row & 3) << 4))) =
            f2bf(sf[r]);
      }
    }
    if (l15 == 0) {
#pragma unroll
      for (int r = 0; r < 4; ++r)
        sumbuf[(wr * 16 + l4 * 4 + r) * 2 + wc] = psum[r];
    }
    __syncthreads();                     // C

    // ---- prefetch next tile under PV ----
    if (jt + 1 < nt) stage(jt + 1);

    // ---- l update, O rescale, PV (rows wr, d-cols wc*128) ----
#pragma unroll
    for (int r = 0; r < 4; ++r) {
      const int row = wr * 16 + l4 * 4 + r;
      l_run[r] = l_run[r] * scl[r] + sumbuf[row * 2] + sumbuf[row * 2 + 1];
    }
#pragma unroll
    for (int df = 0; df < 8; ++df)
#pragma unroll
      for (int r = 0; r < 4; ++r)
        o[df][r] *= scl[r];
    {
      const int arow = wr * 16 + l15;
      s16x8 pa = *(const s16x8*)(P_s + arow * 64 +
                                 ((l4 * 16) ^ ((arow & 3) << 4)));
      const char* kTbase = (const char*)kT_s + (jt & 1) * 16384;
#pragma unroll
      for (int df = 0; df < 8; ++df) {
        const int dl = wc * 128 + df * 16 + l15;
        s16x8 vb = *(const s16x8*)(kTbase + dl * 64 +
                                   ((l4 * 16) ^ ((dl & 3) << 4)));
        o[df] = __builtin_amdgcn_mfma_f32_16x16x32_bf16(pa, vb, o[df], 0, 0, 0);
      }
    }
  }

  // ---- epilogue: O / l -> out ----
  float* ob = out + ((size_t)b * 512 + s * 32 + wr * 16) * 512 + dh * 256 + wc * 128;
#pragma unroll
  for (int r = 0; r < 4; ++r) {
    const float inv = 1.0f / l_run[r];
    const int row = l4 * 4 + r;
#pragma unroll
    for (int df = 0; df < 8; ++df)
      ob[(size_t)row * 512 + df * 16 + l15] = o[df][r] * inv;
  }
}

// ---------------------------------------------------------------------------
extern "C" void kernel_launch(void* const* d_in, const int* in_sizes, int n_in,
                              void* d_out, int out_size, void* d_ws, size_t ws_size,
                              hipStream_t stream) {
  (void)in_sizes; (void)n_in; (void)out_size; (void)ws_size;
  const float* x    = (const float*)d_in[0];   // [16,512,512]
  const float* W    = (const float*)d_in[1];   // [1536,512]
  const float* bias = (const float*)d_in[2];   // [1536]
  float* out = (float*)d_out;                  // [16,512,512]
  char* ws = (char*)d_ws;

  float* cosT            = (float*)(ws);                    // 512*256 f32
  float* sinT            = (float*)(ws + 524288);
  unsigned short* xb     = (unsigned short*)(ws + 1048576); // [8192,512] bf16
  unsigned short* Wb     = (unsigned short*)(ws + 9437184); // [1024,512] bf16
  unsigned short* qb     = (unsigned short*)(ws + 10485760);// [16,512,512] bf16 (scaled)
  unsigned short* kb     = (unsigned short*)(ws + 18874368);// krot
  unsigned short* kTb    = (unsigned short*)(ws + 27262976);// krot^T

  prep<<<2816, 256, 0, stream>>>(x, W, xb, Wb, cosT, sinT);
  gemm_qk<<<dim3(64, 8), 256, 0, stream>>>(xb, Wb, bias, cosT, sinT, qb, kb);
  transpose_bf<<<dim3(16, 16, 16), dim3(32, 8), 0, stream>>>(kb, kTb);
  fused_attn<<<512, 256, ATT_LDS, stream>>>(qb, kb, kTb, out);
}